// Round 3
// baseline (326.169 us; speedup 1.0000x reference)
//
#include <hip/hip_runtime.h>
#include <hip/hip_bf16.h>

#define K_DIM 64

typedef __attribute__((ext_vector_type(8))) __bf16 bf16x8;
typedef __attribute__((ext_vector_type(4))) float  f32x4;

// Kernel 1: row-normalize A and B (fp32) -> bf16 rows in workspace.
// One wave per row: 64 lanes == 64 elements.
__global__ __launch_bounds__(256) void normalize_bf16_kernel(
    const float* __restrict__ A, const float* __restrict__ B,
    __hip_bfloat16* __restrict__ An, __hip_bfloat16* __restrict__ Bn,
    int nA, int nB)
{
    int row  = blockIdx.x * 4 + (threadIdx.x >> 6);
    int lane = threadIdx.x & 63;
    if (row >= nA + nB) return;
    const float*      src = (row < nA) ? A  : B;
    __hip_bfloat16*   dst = (row < nA) ? An : Bn;
    int r = (row < nA) ? row : row - nA;

    float v = src[(size_t)r * K_DIM + lane];
    float s = v * v;
    #pragma unroll
    for (int off = 32; off >= 1; off >>= 1)
        s += __shfl_xor(s, off, 64);
    float inv = 1.0f / fmaxf(sqrtf(s), 1e-8f);   // matches max(||a||, eps)
    dst[(size_t)r * K_DIM + lane] = __float2bfloat16(v * inv);
}

// Kernel 2: C = An * Bn^T via OPERAND-SWAPPED bf16 MFMA. Zero LDS.
// Feeding Bn rows as the MFMA A-operand and An rows as the B-operand gives
// D[row=n][col=m]: lane's col index (lane&15) selects the C *row*, and the 4
// acc registers (row = quad*4+r) are 4 CONSECUTIVE C COLUMNS -> each tile's
// epilogue is a single global_store_dwordx4 straight from the accumulator.
// 128x128 block tile, 4 waves, each wave a 64x64 region (4x4 tiles 16x16).
// Inputs (2 MB total) are L2-resident; C stores are nontemporal (never
// re-read; keeps L2 clean for the input re-reads).
__global__ __launch_bounds__(256) void cosine_gemm_kernel(
    const f32x4* __restrict__ An, const f32x4* __restrict__ Bn,
    float* __restrict__ C, int N)
{
    const int lane = threadIdx.x & 63;
    const int wave = threadIdx.x >> 6;
    const int wm   = wave >> 1;       // 0..1
    const int wn   = wave & 1;        // 0..1
    const int l16  = lane & 15;
    const int quad = lane >> 4;       // 0..3
    const int gm0  = blockIdx.x * 128 + wm * 64;
    const int gn0  = blockIdx.y * 128 + wn * 64;

    // Fragment layout (both operands): [other_dim = lane&15][k = quad*8 + j].
    // A row is 64 bf16 = 8 float4s; float4 index within row = ks*4 + quad.
    bf16x8 bfrag[4][2];
    #pragma unroll
    for (int t = 0; t < 4; ++t) {
        size_t rb = (size_t)(gn0 + t * 16 + l16) * 8;
        bfrag[t][0] = __builtin_bit_cast(bf16x8, Bn[rb + quad]);
        bfrag[t][1] = __builtin_bit_cast(bf16x8, Bn[rb + 4 + quad]);
    }

    #pragma unroll
    for (int tm = 0; tm < 4; ++tm) {
        size_t ra = (size_t)(gm0 + tm * 16 + l16) * 8;
        bf16x8 a0 = __builtin_bit_cast(bf16x8, An[ra + quad]);
        bf16x8 a1 = __builtin_bit_cast(bf16x8, An[ra + 4 + quad]);

        #pragma unroll
        for (int tn = 0; tn < 4; ++tn) {
            f32x4 acc = {0.f, 0.f, 0.f, 0.f};
            // A-op = Bn fragment (rows = n), B-op = An fragment (cols = m):
            // D[n][m] = sum_k Bn[n][k]*An[m][k] = C[m][n]
            acc = __builtin_amdgcn_mfma_f32_16x16x32_bf16(bfrag[tn][0], a0, acc, 0, 0, 0);
            acc = __builtin_amdgcn_mfma_f32_16x16x32_bf16(bfrag[tn][1], a1, acc, 0, 0, 0);
            // D mapping (m89/m91): col = lane&15 -> C row m; row = quad*4+r -> C col n.
            // acc[0..3] are consecutive C columns: one dwordx4 store per tile.
            size_t off = (size_t)(gm0 + tm * 16 + l16) * N
                       + (size_t)(gn0 + tn * 16 + quad * 4);
            __builtin_nontemporal_store(acc, (f32x4*)&C[off]);
        }
    }
}

extern "C" void kernel_launch(void* const* d_in, const int* in_sizes, int n_in,
                              void* d_out, int out_size, void* d_ws, size_t ws_size,
                              hipStream_t stream) {
    const float* A = (const float*)d_in[0];
    const float* B = (const float*)d_in[1];
    int nA = in_sizes[0] / K_DIM;   // 8192
    int nB = in_sizes[1] / K_DIM;   // 8192
    float* C = (float*)d_out;

    __hip_bfloat16* An = (__hip_bfloat16*)d_ws;
    __hip_bfloat16* Bn = An + (size_t)nA * K_DIM;   // 2 MB total in d_ws

    int totalRows = nA + nB;
    normalize_bf16_kernel<<<dim3((totalRows + 3) / 4), dim3(256), 0, stream>>>(
        A, B, An, Bn, nA, nB);

    dim3 grid(nA / 128, nB / 128);
    cosine_gemm_kernel<<<grid, dim3(256), 0, stream>>>(
        (const f32x4*)An, (const f32x4*)Bn, C, nB);
}